// Round 1
// 792.743 us; speedup vs baseline: 1.0241x; 1.0241x over previous
//
#include <hip/hip_runtime.h>

// DeepSeek-V2 expert MLP, fp8-block-dequant weights. T=8192, H=5120, F=1536.
// Pipeline (3 dispatches):
//   1) prep: x f32->bf16; wg,wu dequant->bf16 INTERLEAVED into wq[3072][5120];
//      wd dequant->bf16 wdq[5120][1536].  (unchanged, verified)
//   2) gemm_p<FUSE_SILU>: h = silu/up-pair epilogue of xb @ wq^T.
//   3) gemm_p<plain>: out = h @ wdq^T, f32.
// GEMM structure (new this round): 128x256 C-tile, BK=32, 512 thr = 8 waves
// (2M x 4N, each 64x64 = 4x4 MFMA frags). 4-deep LDS K-tile ring (96 KB),
// prefetch distance 3, ONE raw s_barrier per K-step, counted
// s_waitcnt vmcnt(6) (never 0 in the main loop)  [T3/T4, m218].
// LDS is XOR-swizzled in 16x32 subtiles; global_load_lds keeps a LINEAR dest
// and the INVERSE swizzle is pre-applied to the per-lane global source
// address (rule #21 / m173). Fragment ds_read_b128 drops 8-way -> <=2-way
// bank conflict. s_setprio around the MFMA cluster [T5]; bijective
// XCD-chunked block swizzle [T1] (grids 768 / 1280, both %8==0).

typedef __bf16 bf16x8 __attribute__((ext_vector_type(8)));
typedef float  f32x4  __attribute__((ext_vector_type(4)));

__device__ __forceinline__ void glds16(const __bf16* g, __bf16* l) {
  __builtin_amdgcn_global_load_lds(
      (const __attribute__((address_space(1))) void*)g,
      (__attribute__((address_space(3))) void*)l, 16, 0, 0);
}

// Inverse of the read-side swizzle: for linear 16B LDS chunk c, which logical
// (row, k) must be fetched there. Subtile = 16 rows x 32 cols bf16 = 1024 B,
// storage byte = logical byte ^ ((row&8)<<2) ^ ((row&2)<<3); row bits live in
// byte bits 9..6 (unchanged by the XOR), so the map is an involution.
__device__ __forceinline__ void chunk_rk(int c, int& row, int& k) {
  int s = c >> 6;                 // subtile index (16 rows each)
  int w = (c & 63) << 4;          // storage byte within subtile
  int wl = w ^ (((w >> 9) & 1) << 5) ^ (((w >> 7) & 1) << 4);
  row = (s << 4) + (wl >> 6);
  k = (wl & 63) >> 1;
}

#define SYNC(n)                                                        \
  do {                                                                 \
    __builtin_amdgcn_sched_barrier(0);                                 \
    asm volatile("s_waitcnt vmcnt(" #n ")\n\ts_barrier" ::: "memory"); \
    __builtin_amdgcn_sched_barrier(0);                                 \
  } while (0)

// ---- fused prep: xcast + 3 dequants in one launch (unchanged) -------------
__device__ __forceinline__ void cast8(const float* __restrict__ in,
                                      __bf16* __restrict__ out, size_t idx) {
  f32x4 a = *(const f32x4*)(in + idx);
  f32x4 b = *(const f32x4*)(in + idx + 4);
  bf16x8 o;
#pragma unroll
  for (int i = 0; i < 4; ++i) { o[i] = (__bf16)a[i]; o[i + 4] = (__bf16)b[i]; }
  *(bf16x8*)(out + idx) = o;
}

__device__ __forceinline__ void dq_ilv(const float* __restrict__ w,
                                       const float* __restrict__ s,
                                       __bf16* __restrict__ wq, int r, int tid,
                                       int which) {
  unsigned idx = ((unsigned)r * 256u + (unsigned)tid) * 8u;
  unsigned f = idx / 5120u;
  unsigned h = idx - f * 5120u;
  float sc = s[(f >> 7) * 40 + (h >> 7)];
  f32x4 a = *(const f32x4*)(w + idx);
  f32x4 b = *(const f32x4*)(w + idx + 4);
  bf16x8 o;
#pragma unroll
  for (int i = 0; i < 4; ++i) {
    o[i] = (__bf16)(a[i] * sc);
    o[i + 4] = (__bf16)(b[i] * sc);
  }
  *(bf16x8*)(wq + (size_t)(2 * f + which) * 5120 + h) = o;
}

__device__ __forceinline__ void dq_wd(const float* __restrict__ w,
                                      const float* __restrict__ s,
                                      __bf16* __restrict__ o8, int r, int tid) {
  unsigned idx = ((unsigned)r * 256u + (unsigned)tid) * 8u;
  unsigned f = idx / 1536u;
  unsigned h = idx - f * 1536u;
  float sc = s[(f >> 7) * 12 + (h >> 7)];
  f32x4 a = *(const f32x4*)(w + idx);
  f32x4 b = *(const f32x4*)(w + idx + 4);
  bf16x8 o;
#pragma unroll
  for (int i = 0; i < 4; ++i) {
    o[i] = (__bf16)(a[i] * sc);
    o[i + 4] = (__bf16)(b[i] * sc);
  }
  *(bf16x8*)(o8 + idx) = o;
}

__global__ void prep(const float* __restrict__ x, const float* __restrict__ wg,
                     const float* __restrict__ sg, const float* __restrict__ wu,
                     const float* __restrict__ su, const float* __restrict__ wd,
                     const float* __restrict__ sd, __bf16* __restrict__ xb,
                     __bf16* __restrict__ wq, __bf16* __restrict__ wdq) {
  int bid = blockIdx.x;
  int tid = threadIdx.x;
  if (bid < 20480) {
    cast8(x, xb, ((size_t)bid * 256 + tid) * 8);
  } else if (bid < 24320) {
    dq_ilv(wg, sg, wq, bid - 20480, tid, 0);
  } else if (bid < 28160) {
    dq_ilv(wu, su, wq, bid - 24320, tid, 1);
  } else {
    dq_wd(wd, sd, wdq, bid - 28160, tid);
  }
}

// ---- pipelined GEMM: C = A @ B^T ------------------------------------------
// A:[M,K] bf16, B:[N,K] bf16. Tile 128(M) x 256(N), BK=32.
// LDS ring: 4 buffers x (A 128x32 = 8 KB | B 256x32 = 16 KB) = 96 KB.
template <bool FUSE_SILU, typename OutT>
__global__ __launch_bounds__(512, 2) void gemm_p(
    const __bf16* __restrict__ A, const __bf16* __restrict__ B,
    OutT* __restrict__ C, int M, int N, int K, int ldc, int nbx) {
  __shared__ __bf16 lds[4 * 12288];
  const int tid = threadIdx.x;
  const int lane = tid & 63;
  const int wave = tid >> 6;
  const int lr = lane & 15;

  // bijective XCD-chunked swizzle (gridDim.x % 8 == 0 by construction)
  const int nwg = gridDim.x;
  const int lb = (blockIdx.x & 7) * (nwg >> 3) + (blockIdx.x >> 3);
  const int bx = lb % nbx;
  const int by = lb / nbx;
  const int m0 = by * 128, n0 = bx * 256;

  // per-lane fragment byte offset within a 1 KB subtile, swizzled:
  // logical = lr*64 + (lane>>4)*16 ; XOR row bit3 -> byte bit5, bit1 -> bit4.
  int laneoff = (lr << 6) | ((lane >> 4) << 4);
  laneoff ^= ((lr & 2) << 3) | ((lr & 8) << 2);
  const int wm4 = wave & 4;          // (wave>>2)*4 : A subtile base
  const int wn4 = (wave & 3) << 2;   // wn*4        : B subtile base

  // staging: per thread 1 A-chunk (c=tid) + 2 B-chunks (c=tid, tid+512);
  // inverse-swizzled global source, linear LDS destination.
  int ra, ka, rb0, kb0, rb1, kb1;
  chunk_rk(tid, ra, ka);
  chunk_rk(tid, rb0, kb0);
  chunk_rk(tid + 512, rb1, kb1);
  const __bf16* Ab = A + (size_t)m0 * K;
  const __bf16* Bb = B + (size_t)n0 * K;
  const unsigned offA = (unsigned)ra * K + (unsigned)ka;
  const unsigned offB0 = (unsigned)rb0 * K + (unsigned)kb0;
  const unsigned offB1 = (unsigned)rb1 * K + (unsigned)kb1;

  f32x4 acc[4][4] = {};

  auto STAGE = [&](int t, int bufi) {
    __bf16* lb_ = lds + bufi * 12288;
    const unsigned ko = (unsigned)t << 5;
    glds16(Ab + (offA + ko), lb_ + (tid << 3));
    glds16(Bb + (offB0 + ko), lb_ + 4096 + (tid << 3));
    glds16(Bb + (offB1 + ko), lb_ + 4096 + ((tid + 512) << 3));
  };
  auto COMPUTE = [&](int bufi) {
    const char* base = (const char*)lds + bufi * 24576;
    bf16x8 af[4], bg[4];
#pragma unroll
    for (int i = 0; i < 4; ++i)
      af[i] = *(const bf16x8*)(base + ((wm4 + i) << 10) + laneoff);
#pragma unroll
    for (int j = 0; j < 4; ++j)
      bg[j] = *(const bf16x8*)(base + 8192 + ((wn4 + j) << 10) + laneoff);
    __builtin_amdgcn_s_setprio(1);
#pragma unroll
    for (int j = 0; j < 4; ++j)
#pragma unroll
      for (int i = 0; i < 4; ++i)
        acc[i][j] = __builtin_amdgcn_mfma_f32_16x16x32_bf16(af[i], bg[j],
                                                            acc[i][j], 0, 0, 0);
    __builtin_amdgcn_s_setprio(0);
  };

  const int NT = K >> 5;  // 160 (gemm1) / 48 (gemm2), both >= 4
  // prologue: fill 3 ring slots; vmcnt(6) drains exactly tile 0's 3 loads.
  STAGE(0, 0);
  STAGE(1, 1);
  STAGE(2, 2);
  SYNC(6);
  int cur = 0;
  for (int t = 0; t < NT - 3; ++t) {
    STAGE(t + 3, (cur + 3) & 3);  // slot freed by the barrier that ended t-1
    COMPUTE(cur);
    SYNC(6);                      // drain tile t+1; keep t+2,t+3 in flight
    cur = (cur + 1) & 3;
  }
  COMPUTE(cur); SYNC(3); cur = (cur + 1) & 3;   // t = NT-3
  COMPUTE(cur); SYNC(0); cur = (cur + 1) & 3;   // t = NT-2
  COMPUTE(cur);                                  // t = NT-1

  // C/D layout (m89-verified): col = lane&15, row = (lane>>4)*4 + reg.
  const int colb = n0 + (wn4 << 4) + lr;
  const int rowb = m0 + (wm4 << 4) + ((lane >> 4) << 2);
#pragma unroll
  for (int i = 0; i < 4; ++i)
#pragma unroll
    for (int j = 0; j < 4; ++j)
#pragma unroll
      for (int r = 0; r < 4; ++r) {
        if constexpr (FUSE_SILU) {
          // lanes (2k,2k+1) hold cols (gate_f, up_f) of the same row.
          float v = acc[i][j][r];
          float p = __shfl_xor(v, 1, 64);
          float g = (lane & 1) ? p : v;
          float u = (lane & 1) ? v : p;
          float hv = (g / (1.0f + __expf(-g))) * u;
          if ((lane & 1) == 0)
            C[(size_t)(rowb + i * 16 + r) * ldc + ((colb + j * 16) >> 1)] =
                (OutT)hv;
        } else {
          C[(size_t)(rowb + i * 16 + r) * ldc + (colb + j * 16)] =
              (OutT)acc[i][j][r];
        }
      }
}

extern "C" void kernel_launch(void* const* d_in, const int* in_sizes, int n_in,
                              void* d_out, int out_size, void* d_ws,
                              size_t ws_size, hipStream_t stream) {
  const int Hd = 5120, Fd = 1536, Td = 8192;
  const float* x = (const float*)d_in[0];
  const float* wg = (const float*)d_in[1];
  const float* sg = (const float*)d_in[2];
  const float* wu = (const float*)d_in[3];
  const float* su = (const float*)d_in[4];
  const float* wd = (const float*)d_in[5];
  const float* sd = (const float*)d_in[6];
  float* out = (float*)d_out;

  // ws layout (bf16): xb [T*H] | wq [2F*H] | wdq [H*F] | h [T*F]  ~156 MB
  __bf16* ws = (__bf16*)d_ws;
  const size_t xsz = (size_t)Td * Hd;
  __bf16* xb = ws;
  __bf16* wq = xb + xsz;
  __bf16* wdq = wq + (size_t)2 * Fd * Hd;
  __bf16* hbuf = wdq + (size_t)Hd * Fd;

  prep<<<32000, 256, 0, stream>>>(x, wg, sg, wu, su, wd, sd, xb, wq, wdq);

  // gemm1: [8192 x 3072] = xb @ wq^T, silu-pair epilogue -> h [8192][1536]
  // grid = (3072/256) * (8192/128) = 12 * 64 = 768 = 3 * 256 (no tail)
  gemm_p<true, __bf16><<<768, 512, 0, stream>>>(xb, wq, hbuf, Td, 2 * Fd, Hd,
                                                Fd, 12);

  // gemm2: [8192 x 5120] = h @ wdq^T -> out f32
  // grid = (5120/256) * (8192/128) = 20 * 64 = 1280 = 5 * 256 (no tail)
  gemm_p<false, float><<<1280, 512, 0, stream>>>(hbuf, wdq, out, Td, Hd, Fd,
                                                 Hd, 20);
}

// Round 2
// 740.469 us; speedup vs baseline: 1.0964x; 1.0706x over previous
//
#include <hip/hip_runtime.h>

// DeepSeek-V2 expert MLP, fp8-block-dequant weights. T=8192, H=5120, F=1536.
// Pipeline (3 dispatches):
//   1) prep: x f32->bf16; wg,wu dequant->bf16 INTERLEAVED into wq[3072][5120];
//      wd dequant->bf16 wdq[5120][1536].  (unchanged, verified)
//   2) gemm_p<FUSE_SILU>: h = silu/up-pair epilogue of xb @ wq^T.
//   3) gemm_p<plain>: out = h @ wdq^T, f32.
// GEMM: 128x256 C-tile, BK=32, 512 thr = 8 waves (2M x 4N, wave = 64x64).
// Round-2 changes vs verified round-1 kernel (all else identical):
//   * ring-4 (96 KB) -> ring-3 (72 KB) + __launch_bounds__(512,4)
//     => 2 blocks/CU (16 waves) for inter-block barrier/drain overlap.
//   * 1-phase K-step -> 2-phase template-style interleave [T3]:
//     ph0 {ds_read af x4 + bg x2 | stage A+B0(t+2) | bar | 8 MFMA j01 | bar}
//     ph1 {ds_read bg x2        | stage B1(t+2)   | bar | 8 MFMA j23 |
//          vmcnt(3) bar}   -- loads never drained to 0 in the loop [T4].
// Kept: XOR-swizzled LDS (0 bank conflicts measured), linear glds dest +
// inverse-swizzled global src (rule #21), setprio around MFMA [T5],
// bijective XCD-chunked block swizzle [T1] (grids 768 / 1280, both %8==0).

typedef __bf16 bf16x8 __attribute__((ext_vector_type(8)));
typedef float  f32x4  __attribute__((ext_vector_type(4)));

__device__ __forceinline__ void glds16(const __bf16* g, __bf16* l) {
  __builtin_amdgcn_global_load_lds(
      (const __attribute__((address_space(1))) void*)g,
      (__attribute__((address_space(3))) void*)l, 16, 0, 0);
}

// Inverse of the read-side swizzle: for linear 16B LDS chunk c, which logical
// (row, k) must be fetched there. Subtile = 16 rows x 32 cols bf16 = 1024 B,
// storage byte = logical byte ^ ((row&8)<<2) ^ ((row&2)<<3); row bits live in
// byte bits 9..6 (unchanged by the XOR), so the map is an involution.
__device__ __forceinline__ void chunk_rk(int c, int& row, int& k) {
  int s = c >> 6;                 // subtile index (16 rows each)
  int w = (c & 63) << 4;          // storage byte within subtile
  int wl = w ^ (((w >> 9) & 1) << 5) ^ (((w >> 7) & 1) << 4);
  row = (s << 4) + (wl >> 6);
  k = (wl & 63) >> 1;
}

// raw barrier, schedule-pinned (no vm/lgkm drain -- loads stay in flight)
#define BAR()                                      \
  do {                                             \
    __builtin_amdgcn_sched_barrier(0);             \
    asm volatile("s_barrier" ::: "memory");        \
    __builtin_amdgcn_sched_barrier(0);             \
  } while (0)

#define VMBAR(n)                                                       \
  do {                                                                 \
    __builtin_amdgcn_sched_barrier(0);                                 \
    asm volatile("s_waitcnt vmcnt(" #n ")\n\ts_barrier" ::: "memory"); \
    __builtin_amdgcn_sched_barrier(0);                                 \
  } while (0)

// ---- fused prep: xcast + 3 dequants in one launch (unchanged) -------------
__device__ __forceinline__ void cast8(const float* __restrict__ in,
                                      __bf16* __restrict__ out, size_t idx) {
  f32x4 a = *(const f32x4*)(in + idx);
  f32x4 b = *(const f32x4*)(in + idx + 4);
  bf16x8 o;
#pragma unroll
  for (int i = 0; i < 4; ++i) { o[i] = (__bf16)a[i]; o[i + 4] = (__bf16)b[i]; }
  *(bf16x8*)(out + idx) = o;
}

__device__ __forceinline__ void dq_ilv(const float* __restrict__ w,
                                       const float* __restrict__ s,
                                       __bf16* __restrict__ wq, int r, int tid,
                                       int which) {
  unsigned idx = ((unsigned)r * 256u + (unsigned)tid) * 8u;
  unsigned f = idx / 5120u;
  unsigned h = idx - f * 5120u;
  float sc = s[(f >> 7) * 40 + (h >> 7)];
  f32x4 a = *(const f32x4*)(w + idx);
  f32x4 b = *(const f32x4*)(w + idx + 4);
  bf16x8 o;
#pragma unroll
  for (int i = 0; i < 4; ++i) {
    o[i] = (__bf16)(a[i] * sc);
    o[i + 4] = (__bf16)(b[i] * sc);
  }
  *(bf16x8*)(wq + (size_t)(2 * f + which) * 5120 + h) = o;
}

__device__ __forceinline__ void dq_wd(const float* __restrict__ w,
                                      const float* __restrict__ s,
                                      __bf16* __restrict__ o8, int r, int tid) {
  unsigned idx = ((unsigned)r * 256u + (unsigned)tid) * 8u;
  unsigned f = idx / 1536u;
  unsigned h = idx - f * 1536u;
  float sc = s[(f >> 7) * 12 + (h >> 7)];
  f32x4 a = *(const f32x4*)(w + idx);
  f32x4 b = *(const f32x4*)(w + idx + 4);
  bf16x8 o;
#pragma unroll
  for (int i = 0; i < 4; ++i) {
    o[i] = (__bf16)(a[i] * sc);
    o[i + 4] = (__bf16)(b[i] * sc);
  }
  *(bf16x8*)(o8 + idx) = o;
}

__global__ void prep(const float* __restrict__ x, const float* __restrict__ wg,
                     const float* __restrict__ sg, const float* __restrict__ wu,
                     const float* __restrict__ su, const float* __restrict__ wd,
                     const float* __restrict__ sd, __bf16* __restrict__ xb,
                     __bf16* __restrict__ wq, __bf16* __restrict__ wdq) {
  int bid = blockIdx.x;
  int tid = threadIdx.x;
  if (bid < 20480) {
    cast8(x, xb, ((size_t)bid * 256 + tid) * 8);
  } else if (bid < 24320) {
    dq_ilv(wg, sg, wq, bid - 20480, tid, 0);
  } else if (bid < 28160) {
    dq_ilv(wu, su, wq, bid - 24320, tid, 1);
  } else {
    dq_wd(wd, sd, wdq, bid - 28160, tid);
  }
}

// ---- pipelined GEMM: C = A @ B^T ------------------------------------------
// A:[M,K] bf16, B:[N,K] bf16. Tile 128(M) x 256(N), BK=32.
// LDS ring: 3 buffers x (A 128x32 = 8 KB | B 256x32 = 16 KB) = 72 KB.
template <bool FUSE_SILU, typename OutT>
__global__ __launch_bounds__(512, 4) void gemm_p(
    const __bf16* __restrict__ A, const __bf16* __restrict__ B,
    OutT* __restrict__ C, int M, int N, int K, int ldc, int nbx) {
  __shared__ __bf16 lds[3 * 12288];
  const int tid = threadIdx.x;
  const int lane = tid & 63;
  const int wave = tid >> 6;
  const int lr = lane & 15;

  // bijective XCD-chunked swizzle (gridDim.x % 8 == 0 by construction)
  const int nwg = gridDim.x;
  const int lb = (blockIdx.x & 7) * (nwg >> 3) + (blockIdx.x >> 3);
  const int bx = lb % nbx;
  const int by = lb / nbx;
  const int m0 = by * 128, n0 = bx * 256;

  // per-lane fragment byte offset within a 1 KB subtile, swizzled
  int laneoff = (lr << 6) | ((lane >> 4) << 4);
  laneoff ^= ((lr & 2) << 3) | ((lr & 8) << 2);
  const int wm4 = wave & 4;          // (wave>>2)*4 : A subtile base
  const int wn4 = (wave & 3) << 2;   // wn*4        : B subtile base

  // staging: per thread 1 A-chunk (c=tid) + 2 B-chunks (c=tid, tid+512);
  // inverse-swizzled global source, linear LDS destination.
  int ra, ka, rb0, kb0, rb1, kb1;
  chunk_rk(tid, ra, ka);
  chunk_rk(tid, rb0, kb0);
  chunk_rk(tid + 512, rb1, kb1);
  const __bf16* Ab = A + (size_t)m0 * K;
  const __bf16* Bb = B + (size_t)n0 * K;
  const unsigned offA = (unsigned)ra * K + (unsigned)ka;
  const unsigned offB0 = (unsigned)rb0 * K + (unsigned)kb0;
  const unsigned offB1 = (unsigned)rb1 * K + (unsigned)kb1;

  f32x4 acc[4][4] = {};
  bf16x8 af[4], bg[4];

  // staging split: chunk0 = A + B-lower (2 loads, issued in ph0),
  //                chunk1 = B-upper (1 load, issued in ph1).
  auto STAGE_AB0 = [&](int t, int bufi) {
    __bf16* lb_ = lds + bufi * 12288;
    const unsigned ko = (unsigned)t << 5;
    glds16(Ab + (offA + ko), lb_ + (tid << 3));
    glds16(Bb + (offB0 + ko), lb_ + 4096 + (tid << 3));
  };
  auto STAGE_B1 = [&](int t, int bufi) {
    __bf16* lb_ = lds + bufi * 12288;
    const unsigned ko = (unsigned)t << 5;
    glds16(Bb + (offB1 + ko), lb_ + 4096 + ((tid + 512) << 3));
  };
  auto RD_A = [&](int bufi) {
    const char* base = (const char*)lds + bufi * 24576;
#pragma unroll
    for (int i = 0; i < 4; ++i)
      af[i] = *(const bf16x8*)(base + ((wm4 + i) << 10) + laneoff);
  };
  auto RD_B = [&](int bufi, int j0) {
    const char* base = (const char*)lds + bufi * 24576 + 8192;
#pragma unroll
    for (int j = 0; j < 2; ++j)
      bg[j0 + j] = *(const bf16x8*)(base + ((wn4 + j0 + j) << 10) + laneoff);
  };
  auto MFMA2 = [&](int j0) {
    __builtin_amdgcn_s_setprio(1);
#pragma unroll
    for (int j = 0; j < 2; ++j)
#pragma unroll
      for (int i = 0; i < 4; ++i)
        acc[i][j0 + j] = __builtin_amdgcn_mfma_f32_16x16x32_bf16(
            af[i], bg[j0 + j], acc[i][j0 + j], 0, 0, 0);
    __builtin_amdgcn_s_setprio(0);
  };

  const int NT = K >> 5;  // 160 (gemm1) / 48 (gemm2)

  // prologue: stage tiles 0,1; wait tile0 (3 loads of tile1 stay in flight)
  STAGE_AB0(0, 0);
  STAGE_B1(0, 0);
  STAGE_AB0(1, 1);
  STAGE_B1(1, 1);
  VMBAR(3);

  int cur = 0, stg = 2;
  for (int t = 0; t < NT - 2; ++t) {
    // phase 0: reads (6) + stage chunk0 of t+2, then 8 MFMA (j=0,1)
    RD_A(cur);
    RD_B(cur, 0);
    STAGE_AB0(t + 2, stg);
    BAR();
    MFMA2(0);
    BAR();
    // phase 1: reads (2) + stage chunk1 of t+2, then 8 MFMA (j=2,3)
    RD_B(cur, 2);
    STAGE_B1(t + 2, stg);
    BAR();
    MFMA2(2);
    VMBAR(3);  // t+1 fully staged; t+2's 3 loads stay in flight
    cur = (cur == 2) ? 0 : cur + 1;
    stg = (stg == 2) ? 0 : stg + 1;
  }
  // t = NT-2: no staging; drain to 0 at the end so NT-1 is readable
  RD_A(cur);
  RD_B(cur, 0);
  BAR();
  MFMA2(0);
  BAR();
  RD_B(cur, 2);
  BAR();
  MFMA2(2);
  VMBAR(0);
  cur = (cur == 2) ? 0 : cur + 1;
  // t = NT-1: last tile, no barriers needed after
  RD_A(cur);
  RD_B(cur, 0);
  MFMA2(0);
  RD_B(cur, 2);
  MFMA2(2);

  // C/D layout (m89-verified): col = lane&15, row = (lane>>4)*4 + reg.
  const int colb = n0 + (wn4 << 4) + lr;
  const int rowb = m0 + (wm4 << 4) + ((lane >> 4) << 2);
#pragma unroll
  for (int i = 0; i < 4; ++i)
#pragma unroll
    for (int j = 0; j < 4; ++j)
#pragma unroll
      for (int r = 0; r < 4; ++r) {
        if constexpr (FUSE_SILU) {
          // lanes (2k,2k+1) hold cols (gate_f, up_f) of the same row.
          float v = acc[i][j][r];
          float p = __shfl_xor(v, 1, 64);
          float g = (lane & 1) ? p : v;
          float u = (lane & 1) ? v : p;
          float hv = (g / (1.0f + __expf(-g))) * u;
          if ((lane & 1) == 0)
            C[(size_t)(rowb + i * 16 + r) * ldc + ((colb + j * 16) >> 1)] =
                (OutT)hv;
        } else {
          C[(size_t)(rowb + i * 16 + r) * ldc + (colb + j * 16)] =
              (OutT)acc[i][j][r];
        }
      }
}

extern "C" void kernel_launch(void* const* d_in, const int* in_sizes, int n_in,
                              void* d_out, int out_size, void* d_ws,
                              size_t ws_size, hipStream_t stream) {
  const int Hd = 5120, Fd = 1536, Td = 8192;
  const float* x = (const float*)d_in[0];
  const float* wg = (const float*)d_in[1];
  const float* sg = (const float*)d_in[2];
  const float* wu = (const float*)d_in[3];
  const float* su = (const float*)d_in[4];
  const float* wd = (const float*)d_in[5];
  const float* sd = (const float*)d_in[6];
  float* out = (float*)d_out;

  // ws layout (bf16): xb [T*H] | wq [2F*H] | wdq [H*F] | h [T*F]  ~156 MB
  __bf16* ws = (__bf16*)d_ws;
  const size_t xsz = (size_t)Td * Hd;
  __bf16* xb = ws;
  __bf16* wq = xb + xsz;
  __bf16* wdq = wq + (size_t)2 * Fd * Hd;
  __bf16* hbuf = wdq + (size_t)Hd * Fd;

  prep<<<32000, 256, 0, stream>>>(x, wg, sg, wu, su, wd, sd, xb, wq, wdq);

  // gemm1: [8192 x 3072] = xb @ wq^T, silu-pair epilogue -> h [8192][1536]
  // grid = (3072/256) * (8192/128) = 12 * 64 = 768 (3 full residency rounds
  // at 2 blocks/CU... 768 = 1.5 x 512 resident; TLP covers the seam)
  gemm_p<true, __bf16><<<768, 512, 0, stream>>>(xb, wq, hbuf, Td, 2 * Fd, Hd,
                                                Fd, 12);

  // gemm2: [8192 x 5120] = h @ wdq^T -> out f32
  gemm_p<false, float><<<1280, 512, 0, stream>>>(hbuf, wdq, out, Td, Hd, Fd,
                                                 Hd, 20);
}